// Round 13
// baseline (238.170 us; speedup 1.0000x reference)
//
#include <hip/hip_runtime.h>

#define NB 8
#define NC 512
#define NL 2048
#define NH 8
#define ND 64
#define NHID 512

typedef float f32x4 __attribute__((ext_vector_type(4)));
typedef short bf16x8 __attribute__((ext_vector_type(8)));
typedef unsigned uint32x2 __attribute__((ext_vector_type(2)));
typedef unsigned uint32x4 __attribute__((ext_vector_type(4)));

__device__ __forceinline__ unsigned short f2bf(float x) {
    unsigned u = __float_as_uint(x);
    u += 0x7fffu + ((u >> 16) & 1u);
    return (unsigned short)(u >> 16);
}

// RTNE pair pack (proven R0-R8): lo -> low16, hi -> high16.
__device__ __forceinline__ unsigned pack_bf16_ru(float lo, float hi) {
    unsigned a = __float_as_uint(lo) + 0x8000u;
    unsigned b = __float_as_uint(hi) + 0x8000u;
#if __has_builtin(__builtin_amdgcn_perm)
    return __builtin_amdgcn_perm(b, a, 0x07060302u);
#else
    return (a >> 16) | (b & 0xffff0000u);
#endif
}

// 1-op truncating bf16 pair pack: {hi[31:16], lo[31:16]}.  Used for P only;
// denominator (lsacc) sums the SAME truncated P, so the softmax ratio
// cancels the truncation bias to first order.
__device__ __forceinline__ unsigned pack_bf16_tr(float lo, float hi) {
#if __has_builtin(__builtin_amdgcn_perm)
    return __builtin_amdgcn_perm(__float_as_uint(hi), __float_as_uint(lo), 0x07060302u);
#else
    return (__float_as_uint(lo) >> 16) | (__float_as_uint(hi) & 0xffff0000u);
#endif
}

__device__ __forceinline__ float fexp2(float x) {
#if __has_builtin(__builtin_amdgcn_exp2f)
    return __builtin_amdgcn_exp2f(x);
#else
    return exp2f(x);
#endif
}

// direct global->LDS DMA, 16B per lane; LDS dest = uniform base + lane*16
__device__ __forceinline__ void gll16(const unsigned short* g, unsigned short* l) {
    __builtin_amdgcn_global_load_lds(
        (const __attribute__((address_space(1))) unsigned int*)g,
        (__attribute__((address_space(3))) unsigned int*)l, 16, 0, 0);
}

// C/D-layout -> B-frag relayout (register-only transpose across quads)
__device__ __forceinline__ void pfr_quad_swap(unsigned &a, unsigned &b) {
#if __has_builtin(__builtin_amdgcn_permlane32_swap) && __has_builtin(__builtin_amdgcn_permlane16_swap)
    uint32x2 r0 = __builtin_amdgcn_permlane32_swap(a, b, false, false);
    uint32x2 r1 = __builtin_amdgcn_permlane16_swap(r0[0], r0[1], false, false);
    a = r1[0];
    b = r1[1];
#else
    const int lane = (int)(threadIdx.x & 63);
    const int li = lane & 15, quad = lane >> 4;
    const int s0 = (li + ((quad & 1) << 5)) << 2;
    const int s1 = (li + 16 + ((quad & 1) << 5)) << 2;
    int ra = __builtin_amdgcn_ds_bpermute(s0, (int)a);
    int rb = __builtin_amdgcn_ds_bpermute(s0, (int)b);
    int ta = __builtin_amdgcn_ds_bpermute(s1, (int)a);
    int tb = __builtin_amdgcn_ds_bpermute(s1, (int)b);
    const bool lo = quad < 2;
    a = (unsigned)(lo ? ra : rb);
    b = (unsigned)(lo ? ta : tb);
#endif
}

// ---------------------------------------------------------------------------
// Fused prep: z<8 -> transpose+convert x[b][c][l] fp32 -> xT[b][l][c] bf16
// (phase-1 float4-vectorized; RTNE pair pack; stride-66 LDS rows).
// z==8 -> weight conversion for both tensors (2 chunks/thread).
// ---------------------------------------------------------------------------
__global__ __launch_bounds__(256) void prep_kernel(
    const float* __restrict__ x, unsigned short* __restrict__ xT,
    const float* __restrict__ w_qkv, unsigned short* __restrict__ wqb,
    const float* __restrict__ w_out, unsigned short* __restrict__ wob)
{
    const int tid = threadIdx.x;
    if (blockIdx.z < NB) {
        // ---- xpose tile ----
        __shared__ unsigned short T[64 * 66];
        const int l0 = blockIdx.x * 64, c0 = blockIdx.y * 64, b = blockIdx.z;

        const int cl = tid >> 4, lq = tid & 15;
        #pragma unroll
        for (int i = 0; i < 4; i++) {
            const int c = i * 16 + cl;
            f32x4 v = *(const f32x4*)&x[((size_t)(b * NC + c0 + c)) * NL + l0 + lq * 4];
            unsigned u0 = pack_bf16_ru(v[0], v[1]);
            unsigned u1 = pack_bf16_ru(v[2], v[3]);
            *(unsigned*)&T[c * 66 + lq * 4] = u0;
            *(unsigned*)&T[c * 66 + lq * 4 + 2] = u1;
        }
        __syncthreads();
        const int cg = tid & 7, lr = tid >> 3;
        #pragma unroll
        for (int rep = 0; rep < 2; rep++) {
            const int l = lr + rep * 32;
            unsigned u[4];
            #pragma unroll
            for (int j = 0; j < 4; j++) {
                unsigned short a = T[(cg * 8 + 2 * j) * 66 + l];
                unsigned short c = T[(cg * 8 + 2 * j + 1) * 66 + l];
                u[j] = (unsigned)a | ((unsigned)c << 16);
            }
            uint4 val; val.x = u[0]; val.y = u[1]; val.z = u[2]; val.w = u[3];
            *(uint4*)&xT[((size_t)(b * NL + l0 + l)) * NC + c0 + cg * 8] = val;
        }
    } else {
        // ---- wconv: 256 blocks x 256 threads x 2 chunks = 131072 chunks ----
        const int n8A = 3 * NHID * NC / 8;            // 98304
        const int n8B = NC * NHID / 8;                // 32768
        const int nscale8 = NHID * NC / 8;
        const float scale = 0.125f * 1.44269504088896f;
        const int bl = (int)(blockIdx.x + 32 * blockIdx.y);   // 0..255
        #pragma unroll
        for (int half = 0; half < 2; half++) {
            const int idx = bl * 512 + half * 256 + tid;
            const float* src;
            unsigned short* dst;
            float s;
            size_t off;
            if (idx < n8A) {
                src = w_qkv; dst = wqb; off = (size_t)idx * 8;
                s = (idx < nscale8) ? scale : 1.0f;
            } else {
                const int j = idx - n8A;
                if (j >= n8B) continue;
                src = w_out; dst = wob; off = (size_t)j * 8;
                s = 1.0f;
            }
            float4 a = *(const float4*)&src[off];
            float4 c = *(const float4*)&src[off + 4];
            uint4 val;
            val.x = (unsigned)f2bf(a.x * s) | ((unsigned)f2bf(a.y * s) << 16);
            val.y = (unsigned)f2bf(a.z * s) | ((unsigned)f2bf(a.w * s) << 16);
            val.z = (unsigned)f2bf(c.x * s) | ((unsigned)f2bf(c.y * s) << 16);
            val.w = (unsigned)f2bf(c.z * s) | ((unsigned)f2bf(c.w * s) << 16);
            *(uint4*)&dst[off] = val;
        }
    }
}

// ---------------------------------------------------------------------------
// Kernel 1: QKV projection, restructured: A-operand (xT) now loaded DIRECTLY
// into registers (same pattern as attn's qfr; values bit-identical to the
// old LDS path after swizzle cancellation), 1-iter-ahead reg prefetch.
// Only W stays in LDS (2-buf, gll16+swizzle) -> LDS 64->32 KB, 2->4
// blocks/CU.  MFMA operands/order bitwise identical to R10/R12.
// ---------------------------------------------------------------------------
__global__ __launch_bounds__(256, 4) void qkv_proj_kernel(
    const unsigned short* __restrict__ xT, const unsigned short* __restrict__ wq,
    unsigned short* __restrict__ qb, unsigned short* __restrict__ kb,
    unsigned short* __restrict__ vb)
{
    __shared__ __align__(16) unsigned short Wt[2][128 * 64];  // [o][c], swizzled
    const int tid = threadIdx.x;
    const int wave = tid >> 6, lane = tid & 63;
    const int quad = lane >> 4, li = lane & 15;

    // XCD swizzle: grid 1536 = 8 XCD x 192 slots; slot walks 12 o-tiles
    // within one (b,l) pair before moving to the next pair.
    const int dlin = (int)(blockIdx.x + 12 * (blockIdx.y + 16 * blockIdx.z));
    const int xcd = dlin & 7, slot = dlin >> 3;       // slot 0..191
    const int ot = slot % 12, pl = slot / 12;         // pl 0..15
    const int pg = xcd + 8 * pl;                      // pair 0..127
    const int o0 = ot * 128, l0 = (pg & 15) * 128, b = pg >> 4;

    const f32x4 fzero = {0.f, 0.f, 0.f, 0.f};
    f32x4 acc[2][8];
    #pragma unroll
    for (int mt = 0; mt < 2; mt++)
        #pragma unroll
        for (int nt = 0; nt < 8; nt++) acc[mt][nt] = fzero;

    const int srow = lane >> 3, schk = lane & 7;
    const unsigned short* Xb = xT + ((size_t)(b * NL + l0)) * NC;

    auto stageW = [&](int buf, int c0) {
        #pragma unroll
        for (int i = 0; i < 4; i++) {
            const int r = wave * 32 + i * 8 + srow;
            gll16(wq + (size_t)(o0 + r) * NC + c0 + ((schk ^ (r & 7)) * 8),
                  &Wt[buf][(wave * 32 + i * 8) * 64]);
        }
    };

    bf16x8 aCur[2][2], aNxt[2][2];
    #pragma unroll
    for (int mt = 0; mt < 2; mt++)
        #pragma unroll
        for (int kc = 0; kc < 2; kc++)
            aCur[mt][kc] = *(const bf16x8*)&Xb[(size_t)(wave * 32 + mt * 16 + li) * NC +
                                               kc * 32 + quad * 8];
    stageW(0, 0);
    __syncthreads();

    #pragma unroll 2
    for (int it = 0; it < 8; it++) {
        const int cur = it & 1;
        if (it < 7) {
            const int c1 = (it + 1) * 64;
            #pragma unroll
            for (int mt = 0; mt < 2; mt++)
                #pragma unroll
                for (int kc = 0; kc < 2; kc++)
                    aNxt[mt][kc] = *(const bf16x8*)&Xb[(size_t)(wave * 32 + mt * 16 + li) * NC +
                                                       c1 + kc * 32 + quad * 8];
            stageW(cur ^ 1, c1);
        }

        __builtin_amdgcn_s_setprio(1);
        #pragma unroll
        for (int kc = 0; kc < 2; kc++) {
            const int sw = ((kc * 4 + quad) ^ (li & 7)) * 8;
            #pragma unroll
            for (int nt = 0; nt < 8; nt++) {
                bf16x8 bfr = *(const bf16x8*)&Wt[cur][(nt * 16 + li) * 64 + sw];
                acc[0][nt] = __builtin_amdgcn_mfma_f32_16x16x32_bf16(aCur[0][kc], bfr, acc[0][nt], 0, 0, 0);
                acc[1][nt] = __builtin_amdgcn_mfma_f32_16x16x32_bf16(aCur[1][kc], bfr, acc[1][nt], 0, 0, 0);
            }
        }
        __builtin_amdgcn_s_setprio(0);
        __syncthreads();

        if (it < 7) {
            #pragma unroll
            for (int mt = 0; mt < 2; mt++)
                #pragma unroll
                for (int kc = 0; kc < 2; kc++)
                    aCur[mt][kc] = aNxt[mt][kc];
        }
    }

    // Epilogue.  C/D: row(m=l)=quad*4+reg, col(n=o)=li.  Scale pre-folded.
    const int lr0 = l0 + wave * 32;
    if (o0 < 1024) {
        unsigned short* dst = (o0 < 512) ? qb : kb;
        #pragma unroll
        for (int mt = 0; mt < 2; mt++)
            #pragma unroll
            for (int nt = 0; nt < 8; nt++) {
                int oc = (o0 & 511) + nt * 16 + li;
                int hh = oc >> 6, d = oc & 63;
                size_t base =
                    ((size_t)((b * NH + hh) * NL) + lr0 + mt * 16 + quad * 4) * ND + d;
                #pragma unroll
                for (int r = 0; r < 4; r++)
                    dst[base + (size_t)r * ND] = f2bf(acc[mt][nt][r]);
            }
    } else {
        #pragma unroll
        for (int mt = 0; mt < 2; mt++)
            #pragma unroll
            for (int nt = 0; nt < 8; nt++) {
                int oc = (o0 - 1024) + nt * 16 + li;
                int hh = oc >> 6, d = oc & 63;
                size_t base = ((size_t)((b * NH + hh) * ND) + d) * NL +
                              lr0 + mt * 16 + quad * 4;
                uint2 pv;
                pv.x = (unsigned)f2bf(acc[mt][nt][0]) | ((unsigned)f2bf(acc[mt][nt][1]) << 16);
                pv.y = (unsigned)f2bf(acc[mt][nt][2]) | ((unsigned)f2bf(acc[mt][nt][3]) << 16);
                *(uint2*)&vb[base] = pv;
            }
    }
}

// ---------------------------------------------------------------------------
// Kernel 2: flash attention.  UNCHANGED from R9-R12 (verified 76-77.6us).
// ---------------------------------------------------------------------------
__global__ __launch_bounds__(256, 4) void attn_kernel(
    const unsigned short* __restrict__ qb, const unsigned short* __restrict__ kb,
    const unsigned short* __restrict__ vb, unsigned short* __restrict__ at)
{
    __shared__ __align__(16) unsigned short Kt[2][64 * 64];  // [j][d], swizzled
    __shared__ __align__(16) unsigned short Vt[2][64 * 64];  // [d][j], swizzled
    const int tid = threadIdx.x;
    const int wave = tid >> 6, lane = tid & 63;
    const int quad = lane >> 4, li = lane & 15;

    // XCD swizzle: give each XCD whole (b,h) groups; consecutive slots on
    // an XCD walk qt within a group (all 16 qt share that XCD's L2 K/V).
    const int dlin = (int)(blockIdx.x + 16 * (blockIdx.y + 8 * blockIdx.z));
    const int xcd = dlin & 7, slot = dlin >> 3;       // slot 0..127
    const int qt = slot & 15, gidx = slot >> 4;       // gidx 0..7
    const int g = xcd + 8 * gidx;                     // group 0..63
    const int h = g & 7, b = g >> 3;

    const int bh = b * NH + h;
    const unsigned short* Qb = qb + (size_t)bh * NL * ND;
    const unsigned short* Kb = kb + (size_t)bh * NL * ND;
    const unsigned short* Vb = vb + (size_t)bh * ND * NL;

    bf16x8 qfr[2][2];
    #pragma unroll
    for (int mt = 0; mt < 2; mt++)
        #pragma unroll
        for (int kc = 0; kc < 2; kc++)
            qfr[mt][kc] = *(const bf16x8*)&Qb[(size_t)(qt * 128 + wave * 32 + mt * 16 + li) * ND +
                                             kc * 32 + quad * 8];

    const f32x4 fzero = {0.f, 0.f, 0.f, 0.f};
    f32x4 oacc[2][4];
    #pragma unroll
    for (int mt = 0; mt < 2; mt++)
        #pragma unroll
        for (int dt = 0; dt < 4; dt++) oacc[mt][dt] = fzero;

    // row-sum accumulators: D[m][q] = sum_j P[j][q] via MFMA(ones, P);
    // sum is k-permutation-invariant, every lane gets q=li in every reg.
    f32x4 lsacc0 = fzero, lsacc1 = fzero;
    const short one_bf = (short)0x3F80;  // bf16 1.0
    const bf16x8 ones = {one_bf, one_bf, one_bf, one_bf,
                         one_bf, one_bf, one_bf, one_bf};

    const int rrow = lane >> 3;   // 8 rows per gll16 (row = 128B)
    const int rchk = lane & 7;    // 8 chunks of 16B per row

    // stage one 64-j K/V tile into buffer `buf` (wave-uniform LDS bases)
    auto stage = [&](int buf, int j0) {
        #pragma unroll
        for (int i = 0; i < 2; i++) {
            const int jrow = wave * 16 + i * 8 + rrow;
            gll16(Kb + (size_t)(j0 + jrow) * ND + ((rchk ^ (jrow & 7)) * 8),
                  &Kt[buf][(wave * 16 + i * 8) * 64]);
            const int drow = wave * 16 + i * 8 + rrow;
            gll16(Vb + (size_t)drow * NL + j0 + ((rchk ^ (drow & 7)) * 8),
                  &Vt[buf][(wave * 16 + i * 8) * 64]);
        }
    };

    stage(0, 0);
    __syncthreads();

    #pragma unroll 2
    for (int kt = 0; kt < 32; kt++) {
        const int cur = kt & 1;
        if (kt < 31) stage(cur ^ 1, (kt + 1) * 64);  // prefetch next tile

        __builtin_amdgcn_s_setprio(1);
        #pragma unroll
        for (int c = 0; c < 2; c++) {
            f32x4 st00 = fzero, st01 = fzero, st10 = fzero, st11 = fzero;
            #pragma unroll
            for (int dk = 0; dk < 2; dk++) {
                const int sw = ((dk * 4 + quad) ^ (li & 7)) * 8;
                bf16x8 kf0 = *(const bf16x8*)&Kt[cur][((2 * c + 0) * 16 + li) * 64 + sw];
                bf16x8 kf1 = *(const bf16x8*)&Kt[cur][((2 * c + 1) * 16 + li) * 64 + sw];
                st00 = __builtin_amdgcn_mfma_f32_16x16x32_bf16(kf0, qfr[0][dk], st00, 0, 0, 0);
                st01 = __builtin_amdgcn_mfma_f32_16x16x32_bf16(kf1, qfr[0][dk], st01, 0, 0, 0);
                st10 = __builtin_amdgcn_mfma_f32_16x16x32_bf16(kf0, qfr[1][dk], st10, 0, 0, 0);
                st11 = __builtin_amdgcn_mfma_f32_16x16x32_bf16(kf1, qfr[1][dk], st11, 0, 0, 0);
            }

            unsigned p000, p001, p010, p011, p100, p101, p110, p111;
            {
                float a0 = fexp2(st00[0]), a1 = fexp2(st00[1]),
                      a2 = fexp2(st00[2]), a3 = fexp2(st00[3]);
                float b0 = fexp2(st01[0]), b1 = fexp2(st01[1]),
                      b2 = fexp2(st01[2]), b3 = fexp2(st01[3]);
                p000 = pack_bf16_tr(a0, a1); p001 = pack_bf16_tr(a2, a3);
                p010 = pack_bf16_tr(b0, b1); p011 = pack_bf16_tr(b2, b3);
            }
            {
                float a0 = fexp2(st10[0]), a1 = fexp2(st10[1]),
                      a2 = fexp2(st10[2]), a3 = fexp2(st10[3]);
                float b0 = fexp2(st11[0]), b1 = fexp2(st11[1]),
                      b2 = fexp2(st11[2]), b3 = fexp2(st11[3]);
                p100 = pack_bf16_tr(a0, a1); p101 = pack_bf16_tr(a2, a3);
                p110 = pack_bf16_tr(b0, b1); p111 = pack_bf16_tr(b2, b3);
            }

            pfr_quad_swap(p000, p010);
            pfr_quad_swap(p001, p011);
            pfr_quad_swap(p100, p110);
            pfr_quad_swap(p101, p111);

            uint32x4 u0 = {p000, p001, p010, p011};
            uint32x4 u1 = {p100, p101, p110, p111};
            bf16x8 pf0 = __builtin_bit_cast(bf16x8, u0);
            bf16x8 pf1 = __builtin_bit_cast(bf16x8, u1);

            // row-sums on the matrix pipe (same truncated P as numerator)
            lsacc0 = __builtin_amdgcn_mfma_f32_16x16x32_bf16(ones, pf0, lsacc0, 0, 0, 0);
            lsacc1 = __builtin_amdgcn_mfma_f32_16x16x32_bf16(ones, pf1, lsacc1, 0, 0, 0);

            #pragma unroll
            for (int dt = 0; dt < 4; dt++) {
                const int swv = ((c * 4 + quad) ^ (li & 7)) * 8;
                bf16x8 vfr = *(const bf16x8*)&Vt[cur][(dt * 16 + li) * 64 + swv];
                oacc[0][dt] = __builtin_amdgcn_mfma_f32_16x16x32_bf16(vfr, pf0, oacc[0][dt], 0, 0, 0);
                oacc[1][dt] = __builtin_amdgcn_mfma_f32_16x16x32_bf16(vfr, pf1, oacc[1][dt], 0, 0, 0);
            }
        }
        __builtin_amdgcn_s_setprio(0);
        // one barrier/iter: prefetch landed (vmcnt drain) + all waves done
        // reading buf `cur` before iter kt+2 overwrites it
        __syncthreads();
    }

    #pragma unroll
    for (int mt = 0; mt < 2; mt++) {
        const float rl = 1.0f / (mt ? lsacc1[0] : lsacc0[0]);
        const int l = qt * 128 + wave * 32 + mt * 16 + li;
        #pragma unroll
        for (int dt = 0; dt < 4; dt++) {
            uint2 ov;
            ov.x = (unsigned)f2bf(oacc[mt][dt][0] * rl) |
                   ((unsigned)f2bf(oacc[mt][dt][1] * rl) << 16);
            ov.y = (unsigned)f2bf(oacc[mt][dt][2] * rl) |
                   ((unsigned)f2bf(oacc[mt][dt][3] * rl) << 16);
            *(uint2*)&at[((size_t)(b * NL + l)) * NHID + h * ND + dt * 16 + quad * 4] = ov;
        }
    }
}

// ---------------------------------------------------------------------------
// Kernel 3: output projection.  UNCHANGED from R10-R12 (2-buf prefetch +
// setprio + XCD swizzle).
// ---------------------------------------------------------------------------
__global__ __launch_bounds__(256) void out_proj_kernel(
    const unsigned short* __restrict__ at, const unsigned short* __restrict__ wo,
    const float* __restrict__ bias, float* __restrict__ out)
{
    __shared__ __align__(16) unsigned short Wt[2][128 * 64];  // [o][c], swizzled
    __shared__ __align__(16) unsigned short At[2][128 * 64];  // [l][c], swizzled
    const int tid = threadIdx.x;
    const int wave = tid >> 6, lane = tid & 63;
    const int quad = lane >> 4, li = lane & 15;

    // XCD swizzle: grid 512 = 8 XCD x 64 slots; slot walks 4 o-tiles within
    // one (b,l) pair before moving to the next pair.
    const int dlin = (int)(blockIdx.x + 4 * (blockIdx.y + 16 * blockIdx.z));
    const int xcd = dlin & 7, slot = dlin >> 3;       // slot 0..63
    const int ot = slot & 3, pl = slot >> 2;          // pl 0..15
    const int pg = xcd + 8 * pl;                      // pair 0..127
    const int o0 = ot * 128, l0 = (pg & 15) * 128, b = pg >> 4;

    const f32x4 fzero = {0.f, 0.f, 0.f, 0.f};
    f32x4 acc[2][8];
    #pragma unroll
    for (int mt = 0; mt < 2; mt++)
        #pragma unroll
        for (int nt = 0; nt < 8; nt++) acc[mt][nt] = fzero;

    const int srow = lane >> 3, schk = lane & 7;

    auto stage = [&](int buf, int c0) {
        #pragma unroll
        for (int i = 0; i < 4; i++) {
            const int r = wave * 32 + i * 8 + srow;
            gll16(wo + (size_t)(o0 + r) * NHID + c0 + ((schk ^ (r & 7)) * 8),
                  &Wt[buf][(wave * 32 + i * 8) * 64]);
            gll16(at + ((size_t)(b * NL + l0 + r)) * NHID + c0 + ((schk ^ (r & 7)) * 8),
                  &At[buf][(wave * 32 + i * 8) * 64]);
        }
    };

    stage(0, 0);
    __syncthreads();

    #pragma unroll 2
    for (int it = 0; it < 8; it++) {
        const int cur = it & 1;
        if (it < 7) stage(cur ^ 1, (it + 1) * 64);  // prefetch next K-tile

        __builtin_amdgcn_s_setprio(1);
        #pragma unroll
        for (int kc = 0; kc < 2; kc++) {
            const int sw = ((kc * 4 + quad) ^ (li & 7)) * 8;
            bf16x8 afr0 = *(const bf16x8*)&Wt[cur][(wave * 32 + li) * 64 + sw];
            bf16x8 afr1 = *(const bf16x8*)&Wt[cur][(wave * 32 + 16 + li) * 64 + sw];
            #pragma unroll
            for (int nt = 0; nt < 8; nt++) {
                bf16x8 bfr = *(const bf16x8*)&At[cur][(nt * 16 + li) * 64 + sw];
                acc[0][nt] = __builtin_amdgcn_mfma_f32_16x16x32_bf16(afr0, bfr, acc[0][nt], 0, 0, 0);
                acc[1][nt] = __builtin_amdgcn_mfma_f32_16x16x32_bf16(afr1, bfr, acc[1][nt], 0, 0, 0);
            }
        }
        __builtin_amdgcn_s_setprio(0);
        __syncthreads();
    }

    #pragma unroll
    for (int mt = 0; mt < 2; mt++) {
        int or0 = o0 + wave * 32 + mt * 16 + quad * 4;
        #pragma unroll
        for (int nt = 0; nt < 8; nt++) {
            int l = l0 + nt * 16 + li;
            #pragma unroll
            for (int r = 0; r < 4; r++)
                out[((size_t)(b * NC + or0 + r)) * NL + l] = acc[mt][nt][r] + bias[or0 + r];
        }
    }
}

extern "C" void kernel_launch(void* const* d_in, const int* in_sizes, int n_in,
                              void* d_out, int out_size, void* d_ws, size_t ws_size,
                              hipStream_t stream) {
    const float* x = (const float*)d_in[0];
    const float* w_qkv = (const float*)d_in[1];
    const float* w_out = (const float*)d_in[2];
    const float* b_out = (const float*)d_in[3];
    float* out = (float*)d_out;

    unsigned short* ws = (unsigned short*)d_ws;
    const size_t SZ = (size_t)NB * NH * NL * ND;      // 8.39M elems
    unsigned short* qb = ws;
    unsigned short* kb = qb + SZ;
    unsigned short* vb = kb + SZ;
    unsigned short* at = vb + SZ;
    unsigned short* xT = at + SZ;                     // NB*NL*NC == SZ
    unsigned short* wqb = xT + SZ;
    unsigned short* wob = wqb + (size_t)3 * NHID * NC;

    // fused prep: z<8 xpose (vectorized), z==8 wconv both weights
    prep_kernel<<<dim3(NL / 64, NC / 64, NB + 1), dim3(256), 0, stream>>>(
        x, xT, w_qkv, wqb, w_out, wob);

    qkv_proj_kernel<<<dim3(12, 16, 8), dim3(256), 0, stream>>>(xT, wqb, qb, kb, vb);
    attn_kernel<<<dim3(16, 8, 8), dim3(256), 0, stream>>>(qb, kb, vb, at);
    out_proj_kernel<<<dim3(4, 16, 8), dim3(256), 0, stream>>>(at, wob, b_out, out);
}

// Round 14
// 211.839 us; speedup vs baseline: 1.1243x; 1.1243x over previous
//
#include <hip/hip_runtime.h>

#define NB 8
#define NC 512
#define NL 2048
#define NH 8
#define ND 64
#define NHID 512

typedef float f32x4 __attribute__((ext_vector_type(4)));
typedef short bf16x8 __attribute__((ext_vector_type(8)));
typedef unsigned uint32x2 __attribute__((ext_vector_type(2)));
typedef unsigned uint32x4 __attribute__((ext_vector_type(4)));

__device__ __forceinline__ unsigned short f2bf(float x) {
    unsigned u = __float_as_uint(x);
    u += 0x7fffu + ((u >> 16) & 1u);
    return (unsigned short)(u >> 16);
}

// RTNE pair pack (proven R0-R8): lo -> low16, hi -> high16.
__device__ __forceinline__ unsigned pack_bf16_ru(float lo, float hi) {
    unsigned a = __float_as_uint(lo) + 0x8000u;
    unsigned b = __float_as_uint(hi) + 0x8000u;
#if __has_builtin(__builtin_amdgcn_perm)
    return __builtin_amdgcn_perm(b, a, 0x07060302u);
#else
    return (a >> 16) | (b & 0xffff0000u);
#endif
}

// 1-op truncating bf16 pair pack: {hi[31:16], lo[31:16]}.  Used for P only;
// denominator (lsacc) sums the SAME truncated P, so the softmax ratio
// cancels the truncation bias to first order.
__device__ __forceinline__ unsigned pack_bf16_tr(float lo, float hi) {
#if __has_builtin(__builtin_amdgcn_perm)
    return __builtin_amdgcn_perm(__float_as_uint(hi), __float_as_uint(lo), 0x07060302u);
#else
    return (__float_as_uint(lo) >> 16) | (__float_as_uint(hi) & 0xffff0000u);
#endif
}

__device__ __forceinline__ float fexp2(float x) {
#if __has_builtin(__builtin_amdgcn_exp2f)
    return __builtin_amdgcn_exp2f(x);
#else
    return exp2f(x);
#endif
}

// direct global->LDS DMA, 16B per lane; LDS dest = uniform base + lane*16
__device__ __forceinline__ void gll16(const unsigned short* g, unsigned short* l) {
    __builtin_amdgcn_global_load_lds(
        (const __attribute__((address_space(1))) unsigned int*)g,
        (__attribute__((address_space(3))) unsigned int*)l, 16, 0, 0);
}

// C/D-layout -> B-frag relayout (register-only transpose across quads)
__device__ __forceinline__ void pfr_quad_swap(unsigned &a, unsigned &b) {
#if __has_builtin(__builtin_amdgcn_permlane32_swap) && __has_builtin(__builtin_amdgcn_permlane16_swap)
    uint32x2 r0 = __builtin_amdgcn_permlane32_swap(a, b, false, false);
    uint32x2 r1 = __builtin_amdgcn_permlane16_swap(r0[0], r0[1], false, false);
    a = r1[0];
    b = r1[1];
#else
    const int lane = (int)(threadIdx.x & 63);
    const int li = lane & 15, quad = lane >> 4;
    const int s0 = (li + ((quad & 1) << 5)) << 2;
    const int s1 = (li + 16 + ((quad & 1) << 5)) << 2;
    int ra = __builtin_amdgcn_ds_bpermute(s0, (int)a);
    int rb = __builtin_amdgcn_ds_bpermute(s0, (int)b);
    int ta = __builtin_amdgcn_ds_bpermute(s1, (int)a);
    int tb = __builtin_amdgcn_ds_bpermute(s1, (int)b);
    const bool lo = quad < 2;
    a = (unsigned)(lo ? ra : rb);
    b = (unsigned)(lo ? ta : tb);
#endif
}

// ---------------------------------------------------------------------------
// Fused prep: z<8 -> transpose+convert x[b][c][l] fp32 -> xT[b][l][c] bf16
// (phase-1 float4-vectorized; RTNE pair pack; stride-66 LDS rows).
// z==8 -> weight conversion for both tensors (2 chunks/thread).
// ---------------------------------------------------------------------------
__global__ __launch_bounds__(256) void prep_kernel(
    const float* __restrict__ x, unsigned short* __restrict__ xT,
    const float* __restrict__ w_qkv, unsigned short* __restrict__ wqb,
    const float* __restrict__ w_out, unsigned short* __restrict__ wob)
{
    const int tid = threadIdx.x;
    if (blockIdx.z < NB) {
        // ---- xpose tile ----
        __shared__ unsigned short T[64 * 66];
        const int l0 = blockIdx.x * 64, c0 = blockIdx.y * 64, b = blockIdx.z;

        const int cl = tid >> 4, lq = tid & 15;
        #pragma unroll
        for (int i = 0; i < 4; i++) {
            const int c = i * 16 + cl;
            f32x4 v = *(const f32x4*)&x[((size_t)(b * NC + c0 + c)) * NL + l0 + lq * 4];
            unsigned u0 = pack_bf16_ru(v[0], v[1]);
            unsigned u1 = pack_bf16_ru(v[2], v[3]);
            *(unsigned*)&T[c * 66 + lq * 4] = u0;
            *(unsigned*)&T[c * 66 + lq * 4 + 2] = u1;
        }
        __syncthreads();
        const int cg = tid & 7, lr = tid >> 3;
        #pragma unroll
        for (int rep = 0; rep < 2; rep++) {
            const int l = lr + rep * 32;
            unsigned u[4];
            #pragma unroll
            for (int j = 0; j < 4; j++) {
                unsigned short a = T[(cg * 8 + 2 * j) * 66 + l];
                unsigned short c = T[(cg * 8 + 2 * j + 1) * 66 + l];
                u[j] = (unsigned)a | ((unsigned)c << 16);
            }
            uint4 val; val.x = u[0]; val.y = u[1]; val.z = u[2]; val.w = u[3];
            *(uint4*)&xT[((size_t)(b * NL + l0 + l)) * NC + c0 + cg * 8] = val;
        }
    } else {
        // ---- wconv: 256 blocks x 256 threads x 2 chunks = 131072 chunks ----
        const int n8A = 3 * NHID * NC / 8;            // 98304
        const int n8B = NC * NHID / 8;                // 32768
        const int nscale8 = NHID * NC / 8;
        const float scale = 0.125f * 1.44269504088896f;
        const int bl = (int)(blockIdx.x + 32 * blockIdx.y);   // 0..255
        #pragma unroll
        for (int half = 0; half < 2; half++) {
            const int idx = bl * 512 + half * 256 + tid;
            const float* src;
            unsigned short* dst;
            float s;
            size_t off;
            if (idx < n8A) {
                src = w_qkv; dst = wqb; off = (size_t)idx * 8;
                s = (idx < nscale8) ? scale : 1.0f;
            } else {
                const int j = idx - n8A;
                if (j >= n8B) continue;
                src = w_out; dst = wob; off = (size_t)j * 8;
                s = 1.0f;
            }
            float4 a = *(const float4*)&src[off];
            float4 c = *(const float4*)&src[off + 4];
            uint4 val;
            val.x = (unsigned)f2bf(a.x * s) | ((unsigned)f2bf(a.y * s) << 16);
            val.y = (unsigned)f2bf(a.z * s) | ((unsigned)f2bf(a.w * s) << 16);
            val.z = (unsigned)f2bf(c.x * s) | ((unsigned)f2bf(c.y * s) << 16);
            val.w = (unsigned)f2bf(c.z * s) | ((unsigned)f2bf(c.w * s) << 16);
            *(uint4*)&dst[off] = val;
        }
    }
}

// ---------------------------------------------------------------------------
// Kernel 1: QKV projection.  R10/R12-exact (BK=64, 64KB dbuf for BOTH
// operands, 2-buf prefetch + setprio + XCD swizzle).  R11 (BK=32) and R13
// (A-in-registers) both regressed — gll16's contiguous wave-level DMA is
// the right staging tool; BK=64 / 32-MFMA phases is the sweet spot.
// ---------------------------------------------------------------------------
__global__ __launch_bounds__(256) void qkv_proj_kernel(
    const unsigned short* __restrict__ xT, const unsigned short* __restrict__ wq,
    unsigned short* __restrict__ qb, unsigned short* __restrict__ kb,
    unsigned short* __restrict__ vb)
{
    __shared__ __align__(16) unsigned short Xt[2][128 * 64];  // [l][c], swizzled
    __shared__ __align__(16) unsigned short Wt[2][128 * 64];  // [o][c], swizzled
    const int tid = threadIdx.x;
    const int wave = tid >> 6, lane = tid & 63;
    const int quad = lane >> 4, li = lane & 15;

    // XCD swizzle: grid 1536 = 8 XCD x 192 slots; slot walks 12 o-tiles
    // within one (b,l) pair before moving to the next pair.
    const int dlin = (int)(blockIdx.x + 12 * (blockIdx.y + 16 * blockIdx.z));
    const int xcd = dlin & 7, slot = dlin >> 3;       // slot 0..191
    const int ot = slot % 12, pl = slot / 12;         // pl 0..15
    const int pg = xcd + 8 * pl;                      // pair 0..127
    const int o0 = ot * 128, l0 = (pg & 15) * 128, b = pg >> 4;

    const f32x4 fzero = {0.f, 0.f, 0.f, 0.f};
    f32x4 acc[2][8];
    #pragma unroll
    for (int mt = 0; mt < 2; mt++)
        #pragma unroll
        for (int nt = 0; nt < 8; nt++) acc[mt][nt] = fzero;

    const int srow = lane >> 3, schk = lane & 7;

    auto stage = [&](int buf, int c0) {
        #pragma unroll
        for (int i = 0; i < 4; i++) {
            const int r = wave * 32 + i * 8 + srow;
            gll16(xT + ((size_t)(b * NL + l0 + r)) * NC + c0 + ((schk ^ (r & 7)) * 8),
                  &Xt[buf][(wave * 32 + i * 8) * 64]);
            gll16(wq + (size_t)(o0 + r) * NC + c0 + ((schk ^ (r & 7)) * 8),
                  &Wt[buf][(wave * 32 + i * 8) * 64]);
        }
    };

    stage(0, 0);
    __syncthreads();

    #pragma unroll 2
    for (int it = 0; it < 8; it++) {
        const int cur = it & 1;
        if (it < 7) stage(cur ^ 1, (it + 1) * 64);  // prefetch next K-tile

        __builtin_amdgcn_s_setprio(1);
        #pragma unroll
        for (int kc = 0; kc < 2; kc++) {
            const int sw = ((kc * 4 + quad) ^ (li & 7)) * 8;
            bf16x8 afr0 = *(const bf16x8*)&Xt[cur][(wave * 32 + li) * 64 + sw];
            bf16x8 afr1 = *(const bf16x8*)&Xt[cur][(wave * 32 + 16 + li) * 64 + sw];
            #pragma unroll
            for (int nt = 0; nt < 8; nt++) {
                bf16x8 bfr = *(const bf16x8*)&Wt[cur][(nt * 16 + li) * 64 + sw];
                acc[0][nt] = __builtin_amdgcn_mfma_f32_16x16x32_bf16(afr0, bfr, acc[0][nt], 0, 0, 0);
                acc[1][nt] = __builtin_amdgcn_mfma_f32_16x16x32_bf16(afr1, bfr, acc[1][nt], 0, 0, 0);
            }
        }
        __builtin_amdgcn_s_setprio(0);
        __syncthreads();
    }

    // Epilogue.  C/D: row(m=l)=quad*4+reg, col(n=o)=li.  Scale pre-folded.
    const int lr0 = l0 + wave * 32;
    if (o0 < 1024) {
        unsigned short* dst = (o0 < 512) ? qb : kb;
        #pragma unroll
        for (int mt = 0; mt < 2; mt++)
            #pragma unroll
            for (int nt = 0; nt < 8; nt++) {
                int oc = (o0 & 511) + nt * 16 + li;
                int hh = oc >> 6, d = oc & 63;
                size_t base =
                    ((size_t)((b * NH + hh) * NL) + lr0 + mt * 16 + quad * 4) * ND + d;
                #pragma unroll
                for (int r = 0; r < 4; r++)
                    dst[base + (size_t)r * ND] = f2bf(acc[mt][nt][r]);
            }
    } else {
        #pragma unroll
        for (int mt = 0; mt < 2; mt++)
            #pragma unroll
            for (int nt = 0; nt < 8; nt++) {
                int oc = (o0 - 1024) + nt * 16 + li;
                int hh = oc >> 6, d = oc & 63;
                size_t base = ((size_t)((b * NH + hh) * ND) + d) * NL +
                              lr0 + mt * 16 + quad * 4;
                uint2 pv;
                pv.x = (unsigned)f2bf(acc[mt][nt][0]) | ((unsigned)f2bf(acc[mt][nt][1]) << 16);
                pv.y = (unsigned)f2bf(acc[mt][nt][2]) | ((unsigned)f2bf(acc[mt][nt][3]) << 16);
                *(uint2*)&vb[base] = pv;
            }
    }
}

// ---------------------------------------------------------------------------
// Kernel 2: flash attention.  UNCHANGED from R9-R13 (verified 76-77.6us).
// ---------------------------------------------------------------------------
__global__ __launch_bounds__(256, 4) void attn_kernel(
    const unsigned short* __restrict__ qb, const unsigned short* __restrict__ kb,
    const unsigned short* __restrict__ vb, unsigned short* __restrict__ at)
{
    __shared__ __align__(16) unsigned short Kt[2][64 * 64];  // [j][d], swizzled
    __shared__ __align__(16) unsigned short Vt[2][64 * 64];  // [d][j], swizzled
    const int tid = threadIdx.x;
    const int wave = tid >> 6, lane = tid & 63;
    const int quad = lane >> 4, li = lane & 15;

    // XCD swizzle: give each XCD whole (b,h) groups; consecutive slots on
    // an XCD walk qt within a group (all 16 qt share that XCD's L2 K/V).
    const int dlin = (int)(blockIdx.x + 16 * (blockIdx.y + 8 * blockIdx.z));
    const int xcd = dlin & 7, slot = dlin >> 3;       // slot 0..127
    const int qt = slot & 15, gidx = slot >> 4;       // gidx 0..7
    const int g = xcd + 8 * gidx;                     // group 0..63
    const int h = g & 7, b = g >> 3;

    const int bh = b * NH + h;
    const unsigned short* Qb = qb + (size_t)bh * NL * ND;
    const unsigned short* Kb = kb + (size_t)bh * NL * ND;
    const unsigned short* Vb = vb + (size_t)bh * ND * NL;

    bf16x8 qfr[2][2];
    #pragma unroll
    for (int mt = 0; mt < 2; mt++)
        #pragma unroll
        for (int kc = 0; kc < 2; kc++)
            qfr[mt][kc] = *(const bf16x8*)&Qb[(size_t)(qt * 128 + wave * 32 + mt * 16 + li) * ND +
                                             kc * 32 + quad * 8];

    const f32x4 fzero = {0.f, 0.f, 0.f, 0.f};
    f32x4 oacc[2][4];
    #pragma unroll
    for (int mt = 0; mt < 2; mt++)
        #pragma unroll
        for (int dt = 0; dt < 4; dt++) oacc[mt][dt] = fzero;

    // row-sum accumulators: D[m][q] = sum_j P[j][q] via MFMA(ones, P);
    // sum is k-permutation-invariant, every lane gets q=li in every reg.
    f32x4 lsacc0 = fzero, lsacc1 = fzero;
    const short one_bf = (short)0x3F80;  // bf16 1.0
    const bf16x8 ones = {one_bf, one_bf, one_bf, one_bf,
                         one_bf, one_bf, one_bf, one_bf};

    const int rrow = lane >> 3;   // 8 rows per gll16 (row = 128B)
    const int rchk = lane & 7;    // 8 chunks of 16B per row

    // stage one 64-j K/V tile into buffer `buf` (wave-uniform LDS bases)
    auto stage = [&](int buf, int j0) {
        #pragma unroll
        for (int i = 0; i < 2; i++) {
            const int jrow = wave * 16 + i * 8 + rrow;
            gll16(Kb + (size_t)(j0 + jrow) * ND + ((rchk ^ (jrow & 7)) * 8),
                  &Kt[buf][(wave * 16 + i * 8) * 64]);
            const int drow = wave * 16 + i * 8 + rrow;
            gll16(Vb + (size_t)drow * NL + j0 + ((rchk ^ (drow & 7)) * 8),
                  &Vt[buf][(wave * 16 + i * 8) * 64]);
        }
    };

    stage(0, 0);
    __syncthreads();

    #pragma unroll 2
    for (int kt = 0; kt < 32; kt++) {
        const int cur = kt & 1;
        if (kt < 31) stage(cur ^ 1, (kt + 1) * 64);  // prefetch next tile

        __builtin_amdgcn_s_setprio(1);
        #pragma unroll
        for (int c = 0; c < 2; c++) {
            f32x4 st00 = fzero, st01 = fzero, st10 = fzero, st11 = fzero;
            #pragma unroll
            for (int dk = 0; dk < 2; dk++) {
                const int sw = ((dk * 4 + quad) ^ (li & 7)) * 8;
                bf16x8 kf0 = *(const bf16x8*)&Kt[cur][((2 * c + 0) * 16 + li) * 64 + sw];
                bf16x8 kf1 = *(const bf16x8*)&Kt[cur][((2 * c + 1) * 16 + li) * 64 + sw];
                st00 = __builtin_amdgcn_mfma_f32_16x16x32_bf16(kf0, qfr[0][dk], st00, 0, 0, 0);
                st01 = __builtin_amdgcn_mfma_f32_16x16x32_bf16(kf1, qfr[0][dk], st01, 0, 0, 0);
                st10 = __builtin_amdgcn_mfma_f32_16x16x32_bf16(kf0, qfr[1][dk], st10, 0, 0, 0);
                st11 = __builtin_amdgcn_mfma_f32_16x16x32_bf16(kf1, qfr[1][dk], st11, 0, 0, 0);
            }

            unsigned p000, p001, p010, p011, p100, p101, p110, p111;
            {
                float a0 = fexp2(st00[0]), a1 = fexp2(st00[1]),
                      a2 = fexp2(st00[2]), a3 = fexp2(st00[3]);
                float b0 = fexp2(st01[0]), b1 = fexp2(st01[1]),
                      b2 = fexp2(st01[2]), b3 = fexp2(st01[3]);
                p000 = pack_bf16_tr(a0, a1); p001 = pack_bf16_tr(a2, a3);
                p010 = pack_bf16_tr(b0, b1); p011 = pack_bf16_tr(b2, b3);
            }
            {
                float a0 = fexp2(st10[0]), a1 = fexp2(st10[1]),
                      a2 = fexp2(st10[2]), a3 = fexp2(st10[3]);
                float b0 = fexp2(st11[0]), b1 = fexp2(st11[1]),
                      b2 = fexp2(st11[2]), b3 = fexp2(st11[3]);
                p100 = pack_bf16_tr(a0, a1); p101 = pack_bf16_tr(a2, a3);
                p110 = pack_bf16_tr(b0, b1); p111 = pack_bf16_tr(b2, b3);
            }

            pfr_quad_swap(p000, p010);
            pfr_quad_swap(p001, p011);
            pfr_quad_swap(p100, p110);
            pfr_quad_swap(p101, p111);

            uint32x4 u0 = {p000, p001, p010, p011};
            uint32x4 u1 = {p100, p101, p110, p111};
            bf16x8 pf0 = __builtin_bit_cast(bf16x8, u0);
            bf16x8 pf1 = __builtin_bit_cast(bf16x8, u1);

            // row-sums on the matrix pipe (same truncated P as numerator)
            lsacc0 = __builtin_amdgcn_mfma_f32_16x16x32_bf16(ones, pf0, lsacc0, 0, 0, 0);
            lsacc1 = __builtin_amdgcn_mfma_f32_16x16x32_bf16(ones, pf1, lsacc1, 0, 0, 0);

            #pragma unroll
            for (int dt = 0; dt < 4; dt++) {
                const int swv = ((c * 4 + quad) ^ (li & 7)) * 8;
                bf16x8 vfr = *(const bf16x8*)&Vt[cur][(dt * 16 + li) * 64 + swv];
                oacc[0][dt] = __builtin_amdgcn_mfma_f32_16x16x32_bf16(vfr, pf0, oacc[0][dt], 0, 0, 0);
                oacc[1][dt] = __builtin_amdgcn_mfma_f32_16x16x32_bf16(vfr, pf1, oacc[1][dt], 0, 0, 0);
            }
        }
        __builtin_amdgcn_s_setprio(0);
        // one barrier/iter: prefetch landed (vmcnt drain) + all waves done
        // reading buf `cur` before iter kt+2 overwrites it
        __syncthreads();
    }

    #pragma unroll
    for (int mt = 0; mt < 2; mt++) {
        const float rl = 1.0f / (mt ? lsacc1[0] : lsacc0[0]);
        const int l = qt * 128 + wave * 32 + mt * 16 + li;
        #pragma unroll
        for (int dt = 0; dt < 4; dt++) {
            uint2 ov;
            ov.x = (unsigned)f2bf(oacc[mt][dt][0] * rl) |
                   ((unsigned)f2bf(oacc[mt][dt][1] * rl) << 16);
            ov.y = (unsigned)f2bf(oacc[mt][dt][2] * rl) |
                   ((unsigned)f2bf(oacc[mt][dt][3] * rl) << 16);
            *(uint2*)&at[((size_t)(b * NL + l)) * NHID + h * ND + dt * 16 + quad * 4] = ov;
        }
    }
}

// ---------------------------------------------------------------------------
// Kernel 3: output projection.  UNCHANGED from R10-R13 (2-buf prefetch +
// setprio + XCD swizzle).
// ---------------------------------------------------------------------------
__global__ __launch_bounds__(256) void out_proj_kernel(
    const unsigned short* __restrict__ at, const unsigned short* __restrict__ wo,
    const float* __restrict__ bias, float* __restrict__ out)
{
    __shared__ __align__(16) unsigned short Wt[2][128 * 64];  // [o][c], swizzled
    __shared__ __align__(16) unsigned short At[2][128 * 64];  // [l][c], swizzled
    const int tid = threadIdx.x;
    const int wave = tid >> 6, lane = tid & 63;
    const int quad = lane >> 4, li = lane & 15;

    // XCD swizzle: grid 512 = 8 XCD x 64 slots; slot walks 4 o-tiles within
    // one (b,l) pair before moving to the next pair.
    const int dlin = (int)(blockIdx.x + 4 * (blockIdx.y + 16 * blockIdx.z));
    const int xcd = dlin & 7, slot = dlin >> 3;       // slot 0..63
    const int ot = slot & 3, pl = slot >> 2;          // pl 0..15
    const int pg = xcd + 8 * pl;                      // pair 0..127
    const int o0 = ot * 128, l0 = (pg & 15) * 128, b = pg >> 4;

    const f32x4 fzero = {0.f, 0.f, 0.f, 0.f};
    f32x4 acc[2][8];
    #pragma unroll
    for (int mt = 0; mt < 2; mt++)
        #pragma unroll
        for (int nt = 0; nt < 8; nt++) acc[mt][nt] = fzero;

    const int srow = lane >> 3, schk = lane & 7;

    auto stage = [&](int buf, int c0) {
        #pragma unroll
        for (int i = 0; i < 4; i++) {
            const int r = wave * 32 + i * 8 + srow;
            gll16(wo + (size_t)(o0 + r) * NHID + c0 + ((schk ^ (r & 7)) * 8),
                  &Wt[buf][(wave * 32 + i * 8) * 64]);
            gll16(at + ((size_t)(b * NL + l0 + r)) * NHID + c0 + ((schk ^ (r & 7)) * 8),
                  &At[buf][(wave * 32 + i * 8) * 64]);
        }
    };

    stage(0, 0);
    __syncthreads();

    #pragma unroll 2
    for (int it = 0; it < 8; it++) {
        const int cur = it & 1;
        if (it < 7) stage(cur ^ 1, (it + 1) * 64);  // prefetch next K-tile

        __builtin_amdgcn_s_setprio(1);
        #pragma unroll
        for (int kc = 0; kc < 2; kc++) {
            const int sw = ((kc * 4 + quad) ^ (li & 7)) * 8;
            bf16x8 afr0 = *(const bf16x8*)&Wt[cur][(wave * 32 + li) * 64 + sw];
            bf16x8 afr1 = *(const bf16x8*)&Wt[cur][(wave * 32 + 16 + li) * 64 + sw];
            #pragma unroll
            for (int nt = 0; nt < 8; nt++) {
                bf16x8 bfr = *(const bf16x8*)&At[cur][(nt * 16 + li) * 64 + sw];
                acc[0][nt] = __builtin_amdgcn_mfma_f32_16x16x32_bf16(afr0, bfr, acc[0][nt], 0, 0, 0);
                acc[1][nt] = __builtin_amdgcn_mfma_f32_16x16x32_bf16(afr1, bfr, acc[1][nt], 0, 0, 0);
            }
        }
        __builtin_amdgcn_s_setprio(0);
        __syncthreads();
    }

    #pragma unroll
    for (int mt = 0; mt < 2; mt++) {
        int or0 = o0 + wave * 32 + mt * 16 + quad * 4;
        #pragma unroll
        for (int nt = 0; nt < 8; nt++) {
            int l = l0 + nt * 16 + li;
            #pragma unroll
            for (int r = 0; r < 4; r++)
                out[((size_t)(b * NC + or0 + r)) * NL + l] = acc[mt][nt][r] + bias[or0 + r];
        }
    }
}

extern "C" void kernel_launch(void* const* d_in, const int* in_sizes, int n_in,
                              void* d_out, int out_size, void* d_ws, size_t ws_size,
                              hipStream_t stream) {
    const float* x = (const float*)d_in[0];
    const float* w_qkv = (const float*)d_in[1];
    const float* w_out = (const float*)d_in[2];
    const float* b_out = (const float*)d_in[3];
    float* out = (float*)d_out;

    unsigned short* ws = (unsigned short*)d_ws;
    const size_t SZ = (size_t)NB * NH * NL * ND;      // 8.39M elems
    unsigned short* qb = ws;
    unsigned short* kb = qb + SZ;
    unsigned short* vb = kb + SZ;
    unsigned short* at = vb + SZ;
    unsigned short* xT = at + SZ;                     // NB*NL*NC == SZ
    unsigned short* wqb = xT + SZ;
    unsigned short* wob = wqb + (size_t)3 * NHID * NC;

    // fused prep: z<8 xpose (vectorized), z==8 wconv both weights
    prep_kernel<<<dim3(NL / 64, NC / 64, NB + 1), dim3(256), 0, stream>>>(
        x, xT, w_qkv, wqb, w_out, wob);

    qkv_proj_kernel<<<dim3(12, 16, 8), dim3(256), 0, stream>>>(xT, wqb, qb, kb, vb);
    attn_kernel<<<dim3(16, 8, 8), dim3(256), 0, stream>>>(qb, kb, vb, at);
    out_proj_kernel<<<dim3(4, 16, 8), dim3(256), 0, stream>>>(at, wob, b_out, out);
}

// Round 15
// 205.002 us; speedup vs baseline: 1.1618x; 1.0334x over previous
//
#include <hip/hip_runtime.h>

#define NB 8
#define NC 512
#define NL 2048
#define NH 8
#define ND 64
#define NHID 512

typedef float f32x4 __attribute__((ext_vector_type(4)));
typedef short bf16x8 __attribute__((ext_vector_type(8)));
typedef unsigned uint32x2 __attribute__((ext_vector_type(2)));
typedef unsigned uint32x4 __attribute__((ext_vector_type(4)));

__device__ __forceinline__ unsigned short f2bf(float x) {
    unsigned u = __float_as_uint(x);
    u += 0x7fffu + ((u >> 16) & 1u);
    return (unsigned short)(u >> 16);
}

// RTNE pair pack (proven R0-R8): lo -> low16, hi -> high16.
__device__ __forceinline__ unsigned pack_bf16_ru(float lo, float hi) {
    unsigned a = __float_as_uint(lo) + 0x8000u;
    unsigned b = __float_as_uint(hi) + 0x8000u;
#if __has_builtin(__builtin_amdgcn_perm)
    return __builtin_amdgcn_perm(b, a, 0x07060302u);
#else
    return (a >> 16) | (b & 0xffff0000u);
#endif
}

// 1-op truncating bf16 pair pack: {hi[31:16], lo[31:16]}.  Used for P only;
// denominator (lsacc) sums the SAME truncated P, so the softmax ratio
// cancels the truncation bias to first order.
__device__ __forceinline__ unsigned pack_bf16_tr(float lo, float hi) {
#if __has_builtin(__builtin_amdgcn_perm)
    return __builtin_amdgcn_perm(__float_as_uint(hi), __float_as_uint(lo), 0x07060302u);
#else
    return (__float_as_uint(lo) >> 16) | (__float_as_uint(hi) & 0xffff0000u);
#endif
}

__device__ __forceinline__ float fexp2(float x) {
#if __has_builtin(__builtin_amdgcn_exp2f)
    return __builtin_amdgcn_exp2f(x);
#else
    return exp2f(x);
#endif
}

// direct global->LDS DMA, 16B per lane; LDS dest = uniform base + lane*16
__device__ __forceinline__ void gll16(const unsigned short* g, unsigned short* l) {
    __builtin_amdgcn_global_load_lds(
        (const __attribute__((address_space(1))) unsigned int*)g,
        (__attribute__((address_space(3))) unsigned int*)l, 16, 0, 0);
}

// C/D-layout -> B-frag relayout (register-only transpose across quads)
__device__ __forceinline__ void pfr_quad_swap(unsigned &a, unsigned &b) {
#if __has_builtin(__builtin_amdgcn_permlane32_swap) && __has_builtin(__builtin_amdgcn_permlane16_swap)
    uint32x2 r0 = __builtin_amdgcn_permlane32_swap(a, b, false, false);
    uint32x2 r1 = __builtin_amdgcn_permlane16_swap(r0[0], r0[1], false, false);
    a = r1[0];
    b = r1[1];
#else
    const int lane = (int)(threadIdx.x & 63);
    const int li = lane & 15, quad = lane >> 4;
    const int s0 = (li + ((quad & 1) << 5)) << 2;
    const int s1 = (li + 16 + ((quad & 1) << 5)) << 2;
    int ra = __builtin_amdgcn_ds_bpermute(s0, (int)a);
    int rb = __builtin_amdgcn_ds_bpermute(s0, (int)b);
    int ta = __builtin_amdgcn_ds_bpermute(s1, (int)a);
    int tb = __builtin_amdgcn_ds_bpermute(s1, (int)b);
    const bool lo = quad < 2;
    a = (unsigned)(lo ? ra : rb);
    b = (unsigned)(lo ? ta : tb);
#endif
}

// ---------------------------------------------------------------------------
// Fused prep: z<8 -> transpose+convert x[b][c][l] fp32 -> xT[b][l][c] bf16
// (phase-1 float4-vectorized; RTNE pair pack; stride-66 LDS rows).
// z==8 -> weight conversion for both tensors (2 chunks/thread).
// ---------------------------------------------------------------------------
__global__ __launch_bounds__(256) void prep_kernel(
    const float* __restrict__ x, unsigned short* __restrict__ xT,
    const float* __restrict__ w_qkv, unsigned short* __restrict__ wqb,
    const float* __restrict__ w_out, unsigned short* __restrict__ wob)
{
    const int tid = threadIdx.x;
    if (blockIdx.z < NB) {
        // ---- xpose tile ----
        __shared__ unsigned short T[64 * 66];
        const int l0 = blockIdx.x * 64, c0 = blockIdx.y * 64, b = blockIdx.z;

        const int cl = tid >> 4, lq = tid & 15;
        #pragma unroll
        for (int i = 0; i < 4; i++) {
            const int c = i * 16 + cl;
            f32x4 v = *(const f32x4*)&x[((size_t)(b * NC + c0 + c)) * NL + l0 + lq * 4];
            unsigned u0 = pack_bf16_ru(v[0], v[1]);
            unsigned u1 = pack_bf16_ru(v[2], v[3]);
            *(unsigned*)&T[c * 66 + lq * 4] = u0;
            *(unsigned*)&T[c * 66 + lq * 4 + 2] = u1;
        }
        __syncthreads();
        const int cg = tid & 7, lr = tid >> 3;
        #pragma unroll
        for (int rep = 0; rep < 2; rep++) {
            const int l = lr + rep * 32;
            unsigned u[4];
            #pragma unroll
            for (int j = 0; j < 4; j++) {
                unsigned short a = T[(cg * 8 + 2 * j) * 66 + l];
                unsigned short c = T[(cg * 8 + 2 * j + 1) * 66 + l];
                u[j] = (unsigned)a | ((unsigned)c << 16);
            }
            uint4 val; val.x = u[0]; val.y = u[1]; val.z = u[2]; val.w = u[3];
            *(uint4*)&xT[((size_t)(b * NL + l0 + l)) * NC + c0 + cg * 8] = val;
        }
    } else {
        // ---- wconv: 256 blocks x 256 threads x 2 chunks = 131072 chunks ----
        const int n8A = 3 * NHID * NC / 8;            // 98304
        const int n8B = NC * NHID / 8;                // 32768
        const int nscale8 = NHID * NC / 8;
        const float scale = 0.125f * 1.44269504088896f;
        const int bl = (int)(blockIdx.x + 32 * blockIdx.y);   // 0..255
        #pragma unroll
        for (int half = 0; half < 2; half++) {
            const int idx = bl * 512 + half * 256 + tid;
            const float* src;
            unsigned short* dst;
            float s;
            size_t off;
            if (idx < n8A) {
                src = w_qkv; dst = wqb; off = (size_t)idx * 8;
                s = (idx < nscale8) ? scale : 1.0f;
            } else {
                const int j = idx - n8A;
                if (j >= n8B) continue;
                src = w_out; dst = wob; off = (size_t)j * 8;
                s = 1.0f;
            }
            float4 a = *(const float4*)&src[off];
            float4 c = *(const float4*)&src[off + 4];
            uint4 val;
            val.x = (unsigned)f2bf(a.x * s) | ((unsigned)f2bf(a.y * s) << 16);
            val.y = (unsigned)f2bf(a.z * s) | ((unsigned)f2bf(a.w * s) << 16);
            val.z = (unsigned)f2bf(c.x * s) | ((unsigned)f2bf(c.y * s) << 16);
            val.w = (unsigned)f2bf(c.z * s) | ((unsigned)f2bf(c.w * s) << 16);
            *(uint4*)&dst[off] = val;
        }
    }
}

// ---------------------------------------------------------------------------
// Kernel 1: QKV projection.  R10/R12-exact (BK=64, 64KB dbuf for BOTH
// operands, 2-buf prefetch + setprio + XCD swizzle).
// ---------------------------------------------------------------------------
__global__ __launch_bounds__(256) void qkv_proj_kernel(
    const unsigned short* __restrict__ xT, const unsigned short* __restrict__ wq,
    unsigned short* __restrict__ qb, unsigned short* __restrict__ kb,
    unsigned short* __restrict__ vb)
{
    __shared__ __align__(16) unsigned short Xt[2][128 * 64];  // [l][c], swizzled
    __shared__ __align__(16) unsigned short Wt[2][128 * 64];  // [o][c], swizzled
    const int tid = threadIdx.x;
    const int wave = tid >> 6, lane = tid & 63;
    const int quad = lane >> 4, li = lane & 15;

    // XCD swizzle: grid 1536 = 8 XCD x 192 slots; slot walks 12 o-tiles
    // within one (b,l) pair before moving to the next pair.
    const int dlin = (int)(blockIdx.x + 12 * (blockIdx.y + 16 * blockIdx.z));
    const int xcd = dlin & 7, slot = dlin >> 3;       // slot 0..191
    const int ot = slot % 12, pl = slot / 12;         // pl 0..15
    const int pg = xcd + 8 * pl;                      // pair 0..127
    const int o0 = ot * 128, l0 = (pg & 15) * 128, b = pg >> 4;

    const f32x4 fzero = {0.f, 0.f, 0.f, 0.f};
    f32x4 acc[2][8];
    #pragma unroll
    for (int mt = 0; mt < 2; mt++)
        #pragma unroll
        for (int nt = 0; nt < 8; nt++) acc[mt][nt] = fzero;

    const int srow = lane >> 3, schk = lane & 7;

    auto stage = [&](int buf, int c0) {
        #pragma unroll
        for (int i = 0; i < 4; i++) {
            const int r = wave * 32 + i * 8 + srow;
            gll16(xT + ((size_t)(b * NL + l0 + r)) * NC + c0 + ((schk ^ (r & 7)) * 8),
                  &Xt[buf][(wave * 32 + i * 8) * 64]);
            gll16(wq + (size_t)(o0 + r) * NC + c0 + ((schk ^ (r & 7)) * 8),
                  &Wt[buf][(wave * 32 + i * 8) * 64]);
        }
    };

    stage(0, 0);
    __syncthreads();

    #pragma unroll 2
    for (int it = 0; it < 8; it++) {
        const int cur = it & 1;
        if (it < 7) stage(cur ^ 1, (it + 1) * 64);  // prefetch next K-tile

        __builtin_amdgcn_s_setprio(1);
        #pragma unroll
        for (int kc = 0; kc < 2; kc++) {
            const int sw = ((kc * 4 + quad) ^ (li & 7)) * 8;
            bf16x8 afr0 = *(const bf16x8*)&Xt[cur][(wave * 32 + li) * 64 + sw];
            bf16x8 afr1 = *(const bf16x8*)&Xt[cur][(wave * 32 + 16 + li) * 64 + sw];
            #pragma unroll
            for (int nt = 0; nt < 8; nt++) {
                bf16x8 bfr = *(const bf16x8*)&Wt[cur][(nt * 16 + li) * 64 + sw];
                acc[0][nt] = __builtin_amdgcn_mfma_f32_16x16x32_bf16(afr0, bfr, acc[0][nt], 0, 0, 0);
                acc[1][nt] = __builtin_amdgcn_mfma_f32_16x16x32_bf16(afr1, bfr, acc[1][nt], 0, 0, 0);
            }
        }
        __builtin_amdgcn_s_setprio(0);
        __syncthreads();
    }

    // Epilogue.  C/D: row(m=l)=quad*4+reg, col(n=o)=li.  Scale pre-folded.
    const int lr0 = l0 + wave * 32;
    if (o0 < 1024) {
        unsigned short* dst = (o0 < 512) ? qb : kb;
        #pragma unroll
        for (int mt = 0; mt < 2; mt++)
            #pragma unroll
            for (int nt = 0; nt < 8; nt++) {
                int oc = (o0 & 511) + nt * 16 + li;
                int hh = oc >> 6, d = oc & 63;
                size_t base =
                    ((size_t)((b * NH + hh) * NL) + lr0 + mt * 16 + quad * 4) * ND + d;
                #pragma unroll
                for (int r = 0; r < 4; r++)
                    dst[base + (size_t)r * ND] = f2bf(acc[mt][nt][r]);
            }
    } else {
        #pragma unroll
        for (int mt = 0; mt < 2; mt++)
            #pragma unroll
            for (int nt = 0; nt < 8; nt++) {
                int oc = (o0 - 1024) + nt * 16 + li;
                int hh = oc >> 6, d = oc & 63;
                size_t base = ((size_t)((b * NH + hh) * ND) + d) * NL +
                              lr0 + mt * 16 + quad * 4;
                uint2 pv;
                pv.x = (unsigned)f2bf(acc[mt][nt][0]) | ((unsigned)f2bf(acc[mt][nt][1]) << 16);
                pv.y = (unsigned)f2bf(acc[mt][nt][2]) | ((unsigned)f2bf(acc[mt][nt][3]) << 16);
                *(uint2*)&vb[base] = pv;
            }
    }
}

// ---------------------------------------------------------------------------
// Kernel 2: flash attention.  This round: 8 waves x 32 q-rows (512-thread
// blocks, 256-row q-tiles, grid (8,8,8)=512).  Per-wave inner loop is
// BIT-IDENTICAL to the verified R9 attn (same 32-row wave shape, same
// softmax/PV math); only block aggregation changes: staging traffic halves
// (512 blocks stage the same K/V), total LDS-read traffic unchanged
// (4096 waves, same as R4/R9), residency 2 blocks/CU = 4 waves/SIMD.
// ---------------------------------------------------------------------------
__global__ __launch_bounds__(512, 4) void attn_kernel(
    const unsigned short* __restrict__ qb, const unsigned short* __restrict__ kb,
    const unsigned short* __restrict__ vb, unsigned short* __restrict__ at)
{
    __shared__ __align__(16) unsigned short Kt[2][64 * 64];  // [j][d], swizzled
    __shared__ __align__(16) unsigned short Vt[2][64 * 64];  // [d][j], swizzled
    const int tid = threadIdx.x;
    const int wave = tid >> 6, lane = tid & 63;   // wave 0..7
    const int quad = lane >> 4, li = lane & 15;

    // XCD swizzle: grid 512 = 8 XCD x 64 slots; each XCD owns 8 whole (b,h)
    // groups; slots walk the 8 qt-blocks within a group.
    const int dlin = (int)(blockIdx.x + 8 * (blockIdx.y + 8 * blockIdx.z));
    const int xcd = dlin & 7, slot = dlin >> 3;       // slot 0..63
    const int qt = slot & 7, gidx = slot >> 3;        // gidx 0..7
    const int g = xcd + 8 * gidx;                     // group 0..63
    const int h = g & 7, b = g >> 3;

    const int bh = b * NH + h;
    const unsigned short* Qb = qb + (size_t)bh * NL * ND;
    const unsigned short* Kb = kb + (size_t)bh * NL * ND;
    const unsigned short* Vb = vb + (size_t)bh * ND * NL;

    bf16x8 qfr[2][2];
    #pragma unroll
    for (int mt = 0; mt < 2; mt++)
        #pragma unroll
        for (int kc = 0; kc < 2; kc++)
            qfr[mt][kc] = *(const bf16x8*)&Qb[(size_t)(qt * 256 + wave * 32 + mt * 16 + li) * ND +
                                             kc * 32 + quad * 8];

    const f32x4 fzero = {0.f, 0.f, 0.f, 0.f};
    f32x4 oacc[2][4];
    #pragma unroll
    for (int mt = 0; mt < 2; mt++)
        #pragma unroll
        for (int dt = 0; dt < 4; dt++) oacc[mt][dt] = fzero;

    // row-sum accumulators: D[m][q] = sum_j P[j][q] via MFMA(ones, P);
    // sum is k-permutation-invariant, every lane gets q=li in every reg.
    f32x4 lsacc0 = fzero, lsacc1 = fzero;
    const short one_bf = (short)0x3F80;  // bf16 1.0
    const bf16x8 ones = {one_bf, one_bf, one_bf, one_bf,
                         one_bf, one_bf, one_bf, one_bf};

    const int rrow = lane >> 3;   // 8 rows per gll16 (row = 128B)
    const int rchk = lane & 7;    // 8 chunks of 16B per row

    // stage one 64-j K/V tile: 8 waves x (1 K gll16 + 1 V gll16)
    auto stage = [&](int buf, int j0) {
        const int jrow = wave * 8 + rrow;
        gll16(Kb + (size_t)(j0 + jrow) * ND + ((rchk ^ (jrow & 7)) * 8),
              &Kt[buf][(wave * 8) * 64]);
        const int drow = wave * 8 + rrow;
        gll16(Vb + (size_t)drow * NL + j0 + ((rchk ^ (drow & 7)) * 8),
              &Vt[buf][(wave * 8) * 64]);
    };

    stage(0, 0);
    __syncthreads();

    #pragma unroll 2
    for (int kt = 0; kt < 32; kt++) {
        const int cur = kt & 1;
        if (kt < 31) stage(cur ^ 1, (kt + 1) * 64);  // prefetch next tile

        __builtin_amdgcn_s_setprio(1);
        #pragma unroll
        for (int c = 0; c < 2; c++) {
            f32x4 st00 = fzero, st01 = fzero, st10 = fzero, st11 = fzero;
            #pragma unroll
            for (int dk = 0; dk < 2; dk++) {
                const int sw = ((dk * 4 + quad) ^ (li & 7)) * 8;
                bf16x8 kf0 = *(const bf16x8*)&Kt[cur][((2 * c + 0) * 16 + li) * 64 + sw];
                bf16x8 kf1 = *(const bf16x8*)&Kt[cur][((2 * c + 1) * 16 + li) * 64 + sw];
                st00 = __builtin_amdgcn_mfma_f32_16x16x32_bf16(kf0, qfr[0][dk], st00, 0, 0, 0);
                st01 = __builtin_amdgcn_mfma_f32_16x16x32_bf16(kf1, qfr[0][dk], st01, 0, 0, 0);
                st10 = __builtin_amdgcn_mfma_f32_16x16x32_bf16(kf0, qfr[1][dk], st10, 0, 0, 0);
                st11 = __builtin_amdgcn_mfma_f32_16x16x32_bf16(kf1, qfr[1][dk], st11, 0, 0, 0);
            }

            unsigned p000, p001, p010, p011, p100, p101, p110, p111;
            {
                float a0 = fexp2(st00[0]), a1 = fexp2(st00[1]),
                      a2 = fexp2(st00[2]), a3 = fexp2(st00[3]);
                float b0 = fexp2(st01[0]), b1 = fexp2(st01[1]),
                      b2 = fexp2(st01[2]), b3 = fexp2(st01[3]);
                p000 = pack_bf16_tr(a0, a1); p001 = pack_bf16_tr(a2, a3);
                p010 = pack_bf16_tr(b0, b1); p011 = pack_bf16_tr(b2, b3);
            }
            {
                float a0 = fexp2(st10[0]), a1 = fexp2(st10[1]),
                      a2 = fexp2(st10[2]), a3 = fexp2(st10[3]);
                float b0 = fexp2(st11[0]), b1 = fexp2(st11[1]),
                      b2 = fexp2(st11[2]), b3 = fexp2(st11[3]);
                p100 = pack_bf16_tr(a0, a1); p101 = pack_bf16_tr(a2, a3);
                p110 = pack_bf16_tr(b0, b1); p111 = pack_bf16_tr(b2, b3);
            }

            pfr_quad_swap(p000, p010);
            pfr_quad_swap(p001, p011);
            pfr_quad_swap(p100, p110);
            pfr_quad_swap(p101, p111);

            uint32x4 u0 = {p000, p001, p010, p011};
            uint32x4 u1 = {p100, p101, p110, p111};
            bf16x8 pf0 = __builtin_bit_cast(bf16x8, u0);
            bf16x8 pf1 = __builtin_bit_cast(bf16x8, u1);

            // row-sums on the matrix pipe (same truncated P as numerator)
            lsacc0 = __builtin_amdgcn_mfma_f32_16x16x32_bf16(ones, pf0, lsacc0, 0, 0, 0);
            lsacc1 = __builtin_amdgcn_mfma_f32_16x16x32_bf16(ones, pf1, lsacc1, 0, 0, 0);

            #pragma unroll
            for (int dt = 0; dt < 4; dt++) {
                const int swv = ((c * 4 + quad) ^ (li & 7)) * 8;
                bf16x8 vfr = *(const bf16x8*)&Vt[cur][(dt * 16 + li) * 64 + swv];
                oacc[0][dt] = __builtin_amdgcn_mfma_f32_16x16x32_bf16(vfr, pf0, oacc[0][dt], 0, 0, 0);
                oacc[1][dt] = __builtin_amdgcn_mfma_f32_16x16x32_bf16(vfr, pf1, oacc[1][dt], 0, 0, 0);
            }
        }
        __builtin_amdgcn_s_setprio(0);
        // one barrier/iter: prefetch landed (vmcnt drain) + all waves done
        // reading buf `cur` before iter kt+2 overwrites it
        __syncthreads();
    }

    #pragma unroll
    for (int mt = 0; mt < 2; mt++) {
        const float rl = 1.0f / (mt ? lsacc1[0] : lsacc0[0]);
        const int l = qt * 256 + wave * 32 + mt * 16 + li;
        #pragma unroll
        for (int dt = 0; dt < 4; dt++) {
            uint2 ov;
            ov.x = (unsigned)f2bf(oacc[mt][dt][0] * rl) |
                   ((unsigned)f2bf(oacc[mt][dt][1] * rl) << 16);
            ov.y = (unsigned)f2bf(oacc[mt][dt][2] * rl) |
                   ((unsigned)f2bf(oacc[mt][dt][3] * rl) << 16);
            *(uint2*)&at[((size_t)(b * NL + l)) * NHID + h * ND + dt * 16 + quad * 4] = ov;
        }
    }
}

// ---------------------------------------------------------------------------
// Kernel 3: output projection.  UNCHANGED from R10-R14 (2-buf prefetch +
// setprio + XCD swizzle).
// ---------------------------------------------------------------------------
__global__ __launch_bounds__(256) void out_proj_kernel(
    const unsigned short* __restrict__ at, const unsigned short* __restrict__ wo,
    const float* __restrict__ bias, float* __restrict__ out)
{
    __shared__ __align__(16) unsigned short Wt[2][128 * 64];  // [o][c], swizzled
    __shared__ __align__(16) unsigned short At[2][128 * 64];  // [l][c], swizzled
    const int tid = threadIdx.x;
    const int wave = tid >> 6, lane = tid & 63;
    const int quad = lane >> 4, li = lane & 15;

    // XCD swizzle: grid 512 = 8 XCD x 64 slots; slot walks 4 o-tiles within
    // one (b,l) pair before moving to the next pair.
    const int dlin = (int)(blockIdx.x + 4 * (blockIdx.y + 16 * blockIdx.z));
    const int xcd = dlin & 7, slot = dlin >> 3;       // slot 0..63
    const int ot = slot & 3, pl = slot >> 2;          // pl 0..15
    const int pg = xcd + 8 * pl;                      // pair 0..127
    const int o0 = ot * 128, l0 = (pg & 15) * 128, b = pg >> 4;

    const f32x4 fzero = {0.f, 0.f, 0.f, 0.f};
    f32x4 acc[2][8];
    #pragma unroll
    for (int mt = 0; mt < 2; mt++)
        #pragma unroll
        for (int nt = 0; nt < 8; nt++) acc[mt][nt] = fzero;

    const int srow = lane >> 3, schk = lane & 7;

    auto stage = [&](int buf, int c0) {
        #pragma unroll
        for (int i = 0; i < 4; i++) {
            const int r = wave * 32 + i * 8 + srow;
            gll16(wo + (size_t)(o0 + r) * NHID + c0 + ((schk ^ (r & 7)) * 8),
                  &Wt[buf][(wave * 32 + i * 8) * 64]);
            gll16(at + ((size_t)(b * NL + l0 + r)) * NHID + c0 + ((schk ^ (r & 7)) * 8),
                  &At[buf][(wave * 32 + i * 8) * 64]);
        }
    };

    stage(0, 0);
    __syncthreads();

    #pragma unroll 2
    for (int it = 0; it < 8; it++) {
        const int cur = it & 1;
        if (it < 7) stage(cur ^ 1, (it + 1) * 64);  // prefetch next K-tile

        __builtin_amdgcn_s_setprio(1);
        #pragma unroll
        for (int kc = 0; kc < 2; kc++) {
            const int sw = ((kc * 4 + quad) ^ (li & 7)) * 8;
            bf16x8 afr0 = *(const bf16x8*)&Wt[cur][(wave * 32 + li) * 64 + sw];
            bf16x8 afr1 = *(const bf16x8*)&Wt[cur][(wave * 32 + 16 + li) * 64 + sw];
            #pragma unroll
            for (int nt = 0; nt < 8; nt++) {
                bf16x8 bfr = *(const bf16x8*)&At[cur][(nt * 16 + li) * 64 + sw];
                acc[0][nt] = __builtin_amdgcn_mfma_f32_16x16x32_bf16(afr0, bfr, acc[0][nt], 0, 0, 0);
                acc[1][nt] = __builtin_amdgcn_mfma_f32_16x16x32_bf16(afr1, bfr, acc[1][nt], 0, 0, 0);
            }
        }
        __builtin_amdgcn_s_setprio(0);
        __syncthreads();
    }

    #pragma unroll
    for (int mt = 0; mt < 2; mt++) {
        int or0 = o0 + wave * 32 + mt * 16 + quad * 4;
        #pragma unroll
        for (int nt = 0; nt < 8; nt++) {
            int l = l0 + nt * 16 + li;
            #pragma unroll
            for (int r = 0; r < 4; r++)
                out[((size_t)(b * NC + or0 + r)) * NL + l] = acc[mt][nt][r] + bias[or0 + r];
        }
    }
}

extern "C" void kernel_launch(void* const* d_in, const int* in_sizes, int n_in,
                              void* d_out, int out_size, void* d_ws, size_t ws_size,
                              hipStream_t stream) {
    const float* x = (const float*)d_in[0];
    const float* w_qkv = (const float*)d_in[1];
    const float* w_out = (const float*)d_in[2];
    const float* b_out = (const float*)d_in[3];
    float* out = (float*)d_out;

    unsigned short* ws = (unsigned short*)d_ws;
    const size_t SZ = (size_t)NB * NH * NL * ND;      // 8.39M elems
    unsigned short* qb = ws;
    unsigned short* kb = qb + SZ;
    unsigned short* vb = kb + SZ;
    unsigned short* at = vb + SZ;
    unsigned short* xT = at + SZ;                     // NB*NL*NC == SZ
    unsigned short* wqb = xT + SZ;
    unsigned short* wob = wqb + (size_t)3 * NHID * NC;

    // fused prep: z<8 xpose (vectorized), z==8 wconv both weights
    prep_kernel<<<dim3(NL / 64, NC / 64, NB + 1), dim3(256), 0, stream>>>(
        x, xT, w_qkv, wqb, w_out, wob);

    qkv_proj_kernel<<<dim3(12, 16, 8), dim3(256), 0, stream>>>(xT, wqb, qb, kb, vb);
    attn_kernel<<<dim3(8, 8, 8), dim3(512), 0, stream>>>(qb, kb, vb, at);
    out_proj_kernel<<<dim3(4, 16, 8), dim3(256), 0, stream>>>(at, wob, b_out, out);
}